// Round 11
// baseline (49.548 us; speedup 1.0000x reference)
//
#include <hip/hip_runtime.h>
#include <math.h>

// Problem constants (from reference)
constexpr int kC   = 3;
constexpr int kTIn = 2048;
constexpr int kR   = 64;
constexpr int kTB  = 128;
constexpr float kAlpha = 10.0f;
constexpr float kLog2e = 1.44269504088896f;

constexpr int kK   = 4;              // samples per block (2 pairs)
constexpr int kF4  = kC * kTIn / 4;  // 1536 float4 per sample

#ifndef __has_builtin
#define __has_builtin(x) 0
#endif

static __device__ __forceinline__ float fast_rcp(float x) {
#if __has_builtin(__builtin_amdgcn_rcpf)
    return __builtin_amdgcn_rcpf(x);
#else
    return 1.0f / x;
#endif
}

static __device__ __forceinline__ float fast_exp2(float x) {
#if __has_builtin(__builtin_amdgcn_exp2f)
    return __builtin_amdgcn_exp2f(x);
#else
    return __builtin_exp2f(x);
#endif
}

// ---------------------------------------------------------------------------
// 2-scanner / 2-helper wave specialization (samples are independent).
// 4 waves/block, K=4 samples as 2 pairs, 2048 blocks fully resident.
//   helper h:  loads + pools FULL sample (base+2p+h) -> sp[buf][h];
//              wave-private max == sample max -> red[buf][h].
//   scanner si: scans sample (base+2p+si) from sp[cur][si].
// Half the barriers of the 1-scanner variant -> half the queue-dip events.
// Plain __syncthreads handoff; no hand fences (R8/R9 regression lesson).
// ---------------------------------------------------------------------------
__global__ __launch_bounds__(256, 8)
void fused_encoder_kernel(const float* __restrict__ traces,
                          const float* __restrict__ drive_w,
                          const float* __restrict__ drive_b,
                          const float* __restrict__ freq_raw,
                          const float* __restrict__ q_raw,
                          const float* __restrict__ thr_raw,
                          float* __restrict__ out)
{
    __shared__ float sp[2][2][kTB * 4];   // [buf][sampleInPair][t*4+c], 8 KB
    __shared__ float red[2][2];           // [buf][sampleInPair]

    const int tid  = threadIdx.x;
    const int wave = tid >> 6;
    const int lane = tid & 63;
    const int s0 = blockIdx.x & 3;        // scanner pair {s0, s0^1} spreads SIMDs
    const int s1 = s0 ^ 1;
    const long long base = (long long)blockIdx.x * kK;
    const float4* tr4 = reinterpret_cast<const float4*>(traces);

    const bool isScan = (wave == s0) || (wave == s1);

    if (!isScan) {
        // ================= helper: full-sample load + pool + max ============
        // helpers are the complementary wave pair; h = 0 (lower) / 1 (higher)
        const int h = wave & 1;

        auto pool = [&](long long b, int buf) {
            const float4* src = tr4 + b * kF4 + lane;
            float mloc = 0.0f;
            #pragma unroll
            for (int j = 0; j < 24; ++j) {
                float4 v = src[j * 64];                   // coalesced 1 KB/inst
                float s = (v.x + v.y) + (v.z + v.w);
                s += __shfl_xor(s, 1, 64);
                s += __shfl_xor(s, 2, 64);                // window sum in quad
                mloc = fmaxf(mloc, fabsf(s));
                if ((lane & 3) == 0) {
                    int w = j * 16 + (lane >> 2);         // w = c*128 + t
                    sp[buf][h][(w & 127) * 4 + (w >> 7)] = s;
                }
            }
            #pragma unroll
            for (int off = 4; off <= 32; off <<= 1)       // quads already uniform
                mloc = fmaxf(mloc, __shfl_xor(mloc, off, 64));
            if (lane == 0) red[buf][h] = mloc;            // full-sample max
        };

        pool(base + h, 0);                 // prologue: pair 0 -> buf 0
        __syncthreads();
        for (int p = 0; p < 2; ++p) {
            if (p + 1 < 2) pool(base + 2 * (p + 1) + h, (p + 1) & 1);
            __syncthreads();
        }
    } else {
        // ========== scanner: params (hidden under helpers' pool) + scans ====
        const int si = (wave == s1) ? 1 : 0;
        const int r = lane;
        const float w0   = drive_w[r * kC + 0];
        const float w1   = drive_w[r * kC + 1];
        const float w2   = drive_w[r * kC + 2];
        const float bias = drive_b[r];
        const float freq  = 0.03f + 0.17f / (1.0f + expf(-freq_raw[r]));
        const float qf    = 1.5f + log1pf(expf(q_raw[r]));
        const float decay = expf(-1.0f / qf);
        const float thr   = 0.35f + 0.75f / (1.0f + expf(-thr_raw[r]));
        const float expScale = kAlpha * kLog2e;
        const float thrE  = thr * expScale;

        __syncthreads();
        for (int p = 0; p < 2; ++p) {
            const int cur = p & 1;
            const float mm = red[cur][si];
            const float inv = fast_rcp(fmaxf(mm * (1.0f / 16.0f), 1.0f)) * (1.0f / 16.0f);
            const float v0 = w0 * inv, v1 = w1 * inv, v2 = w2 * inv;
            const float4* pt = reinterpret_cast<const float4*>(sp[cur][si]);

            __builtin_amdgcn_s_setprio(1);
            float state = 0.0f, vel = 0.0f, acc = 0.0f;
            #pragma unroll 8
            for (int t = 0; t < kTB; ++t) {
                float4 pv = pt[t];                    // broadcast ds_read_b128
                float cur_ = fmaf(pv.x, v0, bias);
                cur_ = fmaf(pv.y, v1, cur_);
                cur_ = fmaf(pv.z, v2, cur_);
                vel = fmaf(decay, vel, cur_);
                vel = fmaf(-freq, state, vel);
                state = fmaf(freq, vel, state);
                float e = fast_exp2(fmaf(-expScale, state, thrE));
                float spike = fast_rcp(1.0f + e);
                state = fmaf(-spike, thr, state);
                acc += spike;
            }
            __builtin_amdgcn_s_setprio(0);

            out[(base + 2 * p + si) * kR + r] = acc * (1.0f / kTB);
            __syncthreads();
        }
    }
}

extern "C" void kernel_launch(void* const* d_in, const int* in_sizes, int n_in,
                              void* d_out, int out_size, void* d_ws, size_t ws_size,
                              hipStream_t stream)
{
    const float* traces   = (const float*)d_in[0];
    const float* drive_w  = (const float*)d_in[1];
    const float* drive_b  = (const float*)d_in[2];
    const float* freq_raw = (const float*)d_in[3];
    const float* q_raw    = (const float*)d_in[4];
    const float* thr_raw  = (const float*)d_in[5];
    float* out = (float*)d_out;

    const int totalB = in_sizes[0] / (kC * kTIn);   // 8192
    const int grid = totalB / kK;                   // 2048 blocks, fully resident

    fused_encoder_kernel<<<grid, 256, 0, stream>>>(traces, drive_w, drive_b,
                                                   freq_raw, q_raw, thr_raw, out);
}